// Round 1
// baseline (393.022 us; speedup 1.0000x reference)
//
#include <hip/hip_runtime.h>

#define BB 64
#define SS 512
#define HH 768
#define NBD 5
#define NC 9
#define NR 4096

// ---------------------------------------------------------------------------
// Kernel 1: boundary loss. One 64-lane wave per token, 4 tokens per block.
// Each lane strides H with step 64 (fully coalesced), computes 5 partial dots,
// wave-reduces, lane 0 does log-softmax + masked NLL; block reduces 4 waves
// in LDS, thread 0 does 2 double atomicAdds.
// ---------------------------------------------------------------------------
__global__ __launch_bounds__(256) void bd_kernel(
    const float* __restrict__ wr, const float* __restrict__ Ws,
    const float* __restrict__ bs, const int* __restrict__ tgt,
    const int* __restrict__ seg, double* __restrict__ acc)
{
    const int wid   = threadIdx.x >> 6;
    const int lane  = threadIdx.x & 63;
    const int token = blockIdx.x * 4 + wid;

    const float* row = wr + (size_t)token * HH;

    float dot[NBD] = {0.f, 0.f, 0.f, 0.f, 0.f};
    #pragma unroll
    for (int j = 0; j < HH / 64; ++j) {
        const int h = lane + 64 * j;
        const float x = row[h];
        const float* w = Ws + h * NBD;
        #pragma unroll
        for (int k = 0; k < NBD; ++k) dot[k] += x * w[k];
    }

    #pragma unroll
    for (int k = 0; k < NBD; ++k) {
        #pragma unroll
        for (int off = 32; off; off >>= 1)
            dot[k] += __shfl_xor(dot[k], off);
    }

    __shared__ float s_nll[4];
    __shared__ float s_msk[4];

    if (lane == 0) {
        float l[NBD];
        #pragma unroll
        for (int k = 0; k < NBD; ++k) l[k] = dot[k] + bs[k];
        float m = l[0];
        #pragma unroll
        for (int k = 1; k < NBD; ++k) m = fmaxf(m, l[k]);
        float ssum = 0.f;
        #pragma unroll
        for (int k = 0; k < NBD; ++k) ssum += expf(l[k] - m);
        const float lse = logf(ssum);
        const int   t   = tgt[token];
        const float msk = (float)seg[token];
        const float nll = -(l[t] - m - lse);
        s_nll[wid] = nll * msk;
        s_msk[wid] = msk;
    }
    __syncthreads();
    if (threadIdx.x == 0) {
        const float a = s_nll[0] + s_nll[1] + s_nll[2] + s_nll[3];
        const float c = s_msk[0] + s_msk[1] + s_msk[2] + s_msk[3];
        atomicAdd(acc + 0, (double)a);
        atomicAdd(acc + 1, (double)c);
    }
}

// ---------------------------------------------------------------------------
// Kernel 2: region loss. One 256-thread block per region. Each thread owns
// 3 H-elements (stride 256, coalesced), sums over the region's <=16 rows,
// forms mean, computes 9 partial logits vs W_r, block-reduces, thread 0
// does log-softmax + NLL and one double atomicAdd.
// ---------------------------------------------------------------------------
__global__ __launch_bounds__(256) void region_kernel(
    const float* __restrict__ wr, const float* __restrict__ Wr,
    const float* __restrict__ br, const int* __restrict__ rstart,
    const int* __restrict__ rlen, const int* __restrict__ rbatch,
    const int* __restrict__ rlabel, double* __restrict__ acc)
{
    const int r   = blockIdx.x;
    const int tid = threadIdx.x;
    const int wid  = tid >> 6;
    const int lane = tid & 63;

    const int start = rstart[r];
    const int len   = rlen[r] + 1;          // inclusive end => length+1 rows
    const int b     = rbatch[r];

    const float* base = wr + ((size_t)b * SS + start) * HH;

    float s0 = 0.f, s1 = 0.f, s2 = 0.f;
    for (int row = 0; row < len; ++row) {
        const float* p = base + row * HH;
        s0 += p[tid];
        s1 += p[tid + 256];
        s2 += p[tid + 512];
    }
    const float inv = 1.0f / (float)len;
    const float m0 = s0 * inv, m1 = s1 * inv, m2 = s2 * inv;

    float part[NC];
    #pragma unroll
    for (int c = 0; c < NC; ++c) {
        part[c] = m0 * Wr[tid * NC + c]
                + m1 * Wr[(tid + 256) * NC + c]
                + m2 * Wr[(tid + 512) * NC + c];
    }

    #pragma unroll
    for (int c = 0; c < NC; ++c) {
        #pragma unroll
        for (int off = 32; off; off >>= 1)
            part[c] += __shfl_xor(part[c], off);
    }

    __shared__ float red[4][NC];
    if (lane == 0) {
        #pragma unroll
        for (int c = 0; c < NC; ++c) red[wid][c] = part[c];
    }
    __syncthreads();

    if (tid == 0) {
        float l[NC];
        #pragma unroll
        for (int c = 0; c < NC; ++c)
            l[c] = red[0][c] + red[1][c] + red[2][c] + red[3][c] + br[c];
        float m = l[0];
        #pragma unroll
        for (int c = 1; c < NC; ++c) m = fmaxf(m, l[c]);
        float ssum = 0.f;
        #pragma unroll
        for (int c = 0; c < NC; ++c) ssum += expf(l[c] - m);
        const float lse = logf(ssum);
        const int   t   = rlabel[r];
        const float nll = -(l[t] - m - lse);
        atomicAdd(acc + 2, (double)nll);
    }
}

// ---------------------------------------------------------------------------
// Kernel 3: finalize. out = GAMMA * ent_mean + (1-GAMMA) * bd_masked_mean
// ---------------------------------------------------------------------------
__global__ void fin_kernel(const double* __restrict__ acc, float* __restrict__ out)
{
    if (threadIdx.x == 0) {
        const float ent = (float)(acc[2] / (double)NR);
        const float bd  = (float)(acc[0] / (acc[1] + 1e-6));
        out[0] = 0.3f * ent + 0.7f * bd;
    }
}

extern "C" void kernel_launch(void* const* d_in, const int* in_sizes, int n_in,
                              void* d_out, int out_size, void* d_ws, size_t ws_size,
                              hipStream_t stream)
{
    const float* wr     = (const float*)d_in[0];
    const float* Ws     = (const float*)d_in[1];
    const float* bs     = (const float*)d_in[2];
    const float* Wr     = (const float*)d_in[3];
    const float* br     = (const float*)d_in[4];
    const int*   tgt    = (const int*)d_in[5];
    const int*   seg    = (const int*)d_in[6];
    const int*   rstart = (const int*)d_in[7];
    const int*   rlen   = (const int*)d_in[8];
    const int*   rbatch = (const int*)d_in[9];
    const int*   rlabel = (const int*)d_in[10];

    double* acc = (double*)d_ws;
    hipMemsetAsync(acc, 0, 3 * sizeof(double), stream);

    bd_kernel<<<(BB * SS) / 4, 256, 0, stream>>>(wr, Ws, bs, tgt, seg, acc);
    region_kernel<<<NR, 256, 0, stream>>>(wr, Wr, br, rstart, rlen, rbatch, rlabel, acc);
    fin_kernel<<<1, 64, 0, stream>>>(acc, (float*)d_out);
}

// Round 2
// 190.265 us; speedup vs baseline: 2.0657x; 2.0657x over previous
//
#include <hip/hip_runtime.h>

#define BB 64
#define SS 512
#define HH 768
#define NBD 5
#define NC 9
#define NR 4096

// ---------------------------------------------------------------------------
// Kernel 1: boundary loss partials. 2048 blocks x 256 threads (4 waves).
// Each wave handles 4 tokens (gw + 8192*i). Ws fragment preloaded to regs
// once per wave. Row loads are float4 (16B/lane, coalesced). Per-block
// partial (sum nll*mask, sum mask) written to ws -- NO global atomics.
// ---------------------------------------------------------------------------
__global__ __launch_bounds__(256) void bd_kernel(
    const float* __restrict__ wr, const float* __restrict__ Ws,
    const float* __restrict__ bs, const int* __restrict__ tgt,
    const int* __restrict__ seg, float2* __restrict__ out_part)
{
    const int wid  = threadIdx.x >> 6;
    const int lane = threadIdx.x & 63;
    const int gw   = blockIdx.x * 4 + wid;   // 0..8191

    // Preload this lane's Ws fragment: h = 4*lane + 256*j + e  (60 floats)
    float wreg[3][4][NBD];
    #pragma unroll
    for (int j = 0; j < 3; ++j)
        #pragma unroll
        for (int e = 0; e < 4; ++e) {
            const int h = 4 * lane + 256 * j + e;
            #pragma unroll
            for (int k = 0; k < NBD; ++k)
                wreg[j][e][k] = Ws[h * NBD + k];
        }

    float b0 = bs[0], b1 = bs[1], b2 = bs[2], b3 = bs[3], b4 = bs[4];

    float nll_sum = 0.f, msk_sum = 0.f;

    #pragma unroll
    for (int i = 0; i < 4; ++i) {
        const int token = gw + 8192 * i;
        const float4* row4 = (const float4*)(wr + (size_t)token * HH);

        float4 v[3];
        #pragma unroll
        for (int j = 0; j < 3; ++j) v[j] = row4[lane + 64 * j];

        float dot[NBD] = {0.f, 0.f, 0.f, 0.f, 0.f};
        #pragma unroll
        for (int j = 0; j < 3; ++j) {
            const float x[4] = {v[j].x, v[j].y, v[j].z, v[j].w};
            #pragma unroll
            for (int e = 0; e < 4; ++e)
                #pragma unroll
                for (int k = 0; k < NBD; ++k)
                    dot[k] += x[e] * wreg[j][e][k];
        }

        #pragma unroll
        for (int k = 0; k < NBD; ++k)
            #pragma unroll
            for (int off = 32; off; off >>= 1)
                dot[k] += __shfl_xor(dot[k], off);

        if (lane == 0) {
            float l[NBD] = {dot[0] + b0, dot[1] + b1, dot[2] + b2,
                            dot[3] + b3, dot[4] + b4};
            float m = l[0];
            #pragma unroll
            for (int k = 1; k < NBD; ++k) m = fmaxf(m, l[k]);
            float ssum = 0.f;
            #pragma unroll
            for (int k = 0; k < NBD; ++k) ssum += expf(l[k] - m);
            const float lse = logf(ssum);
            const int   t   = tgt[token];
            const float msk = (float)seg[token];
            nll_sum += msk * (-(l[t] - m - lse));
            msk_sum += msk;
        }
    }

    __shared__ float s_n[4], s_m[4];
    if (lane == 0) { s_n[wid] = nll_sum; s_m[wid] = msk_sum; }
    __syncthreads();
    if (threadIdx.x == 0) {
        out_part[blockIdx.x] =
            make_float2(s_n[0] + s_n[1] + s_n[2] + s_n[3],
                        s_m[0] + s_m[1] + s_m[2] + s_m[3]);
    }
}

// ---------------------------------------------------------------------------
// Kernel 2: region loss. One 192-thread block (3 waves) per region; each
// thread owns one float4 of H. Rows are L3-warm from kernel 1. Per-region
// nll written to ws -- NO global atomics.
// ---------------------------------------------------------------------------
__global__ __launch_bounds__(192) void region_kernel(
    const float* __restrict__ wr, const float* __restrict__ Wr,
    const float* __restrict__ br, const int* __restrict__ rstart,
    const int* __restrict__ rlen, const int* __restrict__ rbatch,
    const int* __restrict__ rlabel, float* __restrict__ out_nll)
{
    const int r    = blockIdx.x;
    const int tid  = threadIdx.x;
    const int wid  = tid >> 6;
    const int lane = tid & 63;

    const int start = rstart[r];
    const int len   = rlen[r] + 1;   // inclusive end => length+1 rows
    const int b     = rbatch[r];

    const float4* base4 =
        (const float4*)wr + ((size_t)b * SS + start) * (HH / 4);

    float s0 = 0.f, s1 = 0.f, s2 = 0.f, s3 = 0.f;
    for (int row = 0; row < len; ++row) {
        const float4 v = base4[row * (HH / 4) + tid];
        s0 += v.x; s1 += v.y; s2 += v.z; s3 += v.w;
    }
    const float inv = 1.0f / (float)len;
    const float m[4] = {s0 * inv, s1 * inv, s2 * inv, s3 * inv};

    float part[NC];
    #pragma unroll
    for (int c = 0; c < NC; ++c) part[c] = 0.f;
    #pragma unroll
    for (int e = 0; e < 4; ++e) {
        const int h = 4 * tid + e;
        #pragma unroll
        for (int c = 0; c < NC; ++c) part[c] += m[e] * Wr[h * NC + c];
    }

    #pragma unroll
    for (int c = 0; c < NC; ++c)
        #pragma unroll
        for (int off = 32; off; off >>= 1)
            part[c] += __shfl_xor(part[c], off);

    __shared__ float red[3][NC];
    if (lane == 0) {
        #pragma unroll
        for (int c = 0; c < NC; ++c) red[wid][c] = part[c];
    }
    __syncthreads();

    if (tid == 0) {
        float l[NC];
        #pragma unroll
        for (int c = 0; c < NC; ++c)
            l[c] = red[0][c] + red[1][c] + red[2][c] + br[c];
        float mx = l[0];
        #pragma unroll
        for (int c = 1; c < NC; ++c) mx = fmaxf(mx, l[c]);
        float ssum = 0.f;
        #pragma unroll
        for (int c = 0; c < NC; ++c) ssum += expf(l[c] - mx);
        const float lse = logf(ssum);
        const int   t   = rlabel[r];
        out_nll[r] = -(l[t] - mx - lse);
    }
}

// ---------------------------------------------------------------------------
// Kernel 3: final reduction (1 block, 256 threads, f64 accumulation).
// ---------------------------------------------------------------------------
__global__ __launch_bounds__(256) void fin_kernel(
    const float2* __restrict__ bdp, const float* __restrict__ rnll,
    float* __restrict__ out)
{
    const int tid  = threadIdx.x;
    const int wid  = tid >> 6;
    const int lane = tid & 63;

    double a = 0.0, c = 0.0, e = 0.0;
    for (int i = tid; i < 2048; i += 256) {
        const float2 p = bdp[i];
        a += (double)p.x;
        c += (double)p.y;
    }
    for (int i = tid; i < 4096; i += 256) e += (double)rnll[i];

    #pragma unroll
    for (int off = 32; off; off >>= 1) {
        a += __shfl_xor(a, off);
        c += __shfl_xor(c, off);
        e += __shfl_xor(e, off);
    }

    __shared__ double sa[4], sc[4], se[4];
    if (lane == 0) { sa[wid] = a; sc[wid] = c; se[wid] = e; }
    __syncthreads();

    if (tid == 0) {
        const double A = sa[0] + sa[1] + sa[2] + sa[3];
        const double C = sc[0] + sc[1] + sc[2] + sc[3];
        const double E = se[0] + se[1] + se[2] + se[3];
        const float ent = (float)(E / (double)NR);
        const float bd  = (float)(A / (C + 1e-6));
        out[0] = 0.3f * ent + 0.7f * bd;
    }
}

extern "C" void kernel_launch(void* const* d_in, const int* in_sizes, int n_in,
                              void* d_out, int out_size, void* d_ws, size_t ws_size,
                              hipStream_t stream)
{
    const float* wr     = (const float*)d_in[0];
    const float* Ws     = (const float*)d_in[1];
    const float* bs     = (const float*)d_in[2];
    const float* Wr     = (const float*)d_in[3];
    const float* br     = (const float*)d_in[4];
    const int*   tgt    = (const int*)d_in[5];
    const int*   seg    = (const int*)d_in[6];
    const int*   rstart = (const int*)d_in[7];
    const int*   rlen   = (const int*)d_in[8];
    const int*   rbatch = (const int*)d_in[9];
    const int*   rlabel = (const int*)d_in[10];

    float2* bdp  = (float2*)d_ws;                          // 2048 * 8 B
    float*  rnll = (float*)((char*)d_ws + 2048 * sizeof(float2)); // 4096 * 4 B

    bd_kernel<<<2048, 256, 0, stream>>>(wr, Ws, bs, tgt, seg, bdp);
    region_kernel<<<NR, 192, 0, stream>>>(wr, Wr, br, rstart, rlen, rbatch,
                                          rlabel, rnll);
    fin_kernel<<<1, 256, 0, stream>>>(bdp, rnll, (float*)d_out);
}

// Round 3
// 190.262 us; speedup vs baseline: 2.0657x; 1.0000x over previous
//
#include <hip/hip_runtime.h>

#define BB 64
#define SS 512
#define HH 768
#define NBD 5
#define NC 9
#define NR 4096
#define NB_BD 2048
#define NBLK (NB_BD + NR)   // 6144 blocks total

// ---------------------------------------------------------------------------
// Fused kernel. bid%3==0 -> boundary block (bid/3 in [0,2048)); else region
// block (r = bid - bid/3 - 1 in [0,4096)). Interleaving keeps the HBM-
// streaming bd blocks and the L3/latency-bound region blocks co-resident.
// ---------------------------------------------------------------------------
__global__ __launch_bounds__(256) void main_kernel(
    const float* __restrict__ wr, const float* __restrict__ Ws,
    const float* __restrict__ bs, const int* __restrict__ tgt,
    const int* __restrict__ seg,
    const float* __restrict__ Wr, const float* __restrict__ br,
    const int* __restrict__ rstart, const int* __restrict__ rlen,
    const int* __restrict__ rbatch, const int* __restrict__ rlabel,
    float2* __restrict__ bd_part, float* __restrict__ rnll)
{
    const int tid  = threadIdx.x;
    const int wid  = tid >> 6;
    const int lane = tid & 63;
    const int bid  = blockIdx.x;

    if (bid % 3 == 0) {
        // ================= boundary part =================
        const int bb = bid / 3;          // 0..2047
        const int gw = bb * 4 + wid;     // 0..8191

        // Preload this lane's Ws fragment as contiguous float4s:
        // h in {4*lane + 256*j + e}, Ws rows are 5 floats -> 20 contiguous
        // floats per (lane,j) = 5 float4 loads.
        float wreg[3][4][NBD];
        #pragma unroll
        for (int j = 0; j < 3; ++j) {
            const float4* wp = (const float4*)(Ws + (4 * lane + 256 * j) * NBD);
            #pragma unroll
            for (int p = 0; p < 5; ++p) {
                const float4 f = wp[p];
                const float vv[4] = {f.x, f.y, f.z, f.w};
                #pragma unroll
                for (int q = 0; q < 4; ++q) {
                    const int flat = 4 * p + q;           // 0..19
                    wreg[j][flat / NBD][flat % NBD] = vv[q];
                }
            }
        }

        const float b0 = bs[0], b1 = bs[1], b2 = bs[2], b3 = bs[3], b4 = bs[4];

        float nll_sum = 0.f, msk_sum = 0.f;

        #pragma unroll
        for (int i = 0; i < 4; ++i) {
            const int token = gw + 8192 * i;
            const float4* row4 = (const float4*)(wr + (size_t)token * HH);

            float4 v[3];
            #pragma unroll
            for (int j = 0; j < 3; ++j) v[j] = row4[lane + 64 * j];

            float dot[NBD] = {0.f, 0.f, 0.f, 0.f, 0.f};
            #pragma unroll
            for (int j = 0; j < 3; ++j) {
                const float x[4] = {v[j].x, v[j].y, v[j].z, v[j].w};
                #pragma unroll
                for (int e = 0; e < 4; ++e)
                    #pragma unroll
                    for (int k = 0; k < NBD; ++k)
                        dot[k] += x[e] * wreg[j][e][k];
            }

            #pragma unroll
            for (int k = 0; k < NBD; ++k)
                #pragma unroll
                for (int off = 32; off; off >>= 1)
                    dot[k] += __shfl_xor(dot[k], off);

            if (lane == 0) {
                float l[NBD] = {dot[0] + b0, dot[1] + b1, dot[2] + b2,
                                dot[3] + b3, dot[4] + b4};
                float m = l[0];
                #pragma unroll
                for (int k = 1; k < NBD; ++k) m = fmaxf(m, l[k]);
                float ssum = 0.f;
                #pragma unroll
                for (int k = 0; k < NBD; ++k) ssum += expf(l[k] - m);
                const float lse = logf(ssum);
                const int   t   = tgt[token];
                const float msk = (float)seg[token];
                nll_sum += msk * (-(l[t] - m - lse));
                msk_sum += msk;
            }
        }

        __shared__ float s_n[4], s_m[4];
        if (lane == 0) { s_n[wid] = nll_sum; s_m[wid] = msk_sum; }
        __syncthreads();
        if (tid == 0) {
            bd_part[bb] = make_float2(s_n[0] + s_n[1] + s_n[2] + s_n[3],
                                      s_m[0] + s_m[1] + s_m[2] + s_m[3]);
        }
    } else {
        // ================= region part =================
        const int r     = bid - bid / 3 - 1;   // 0..4095
        const int start = rstart[r];
        const int len   = rlen[r] + 1;         // inclusive end -> len+1 rows
        const int b     = rbatch[r];

        const float4* base4 =
            (const float4*)wr + ((size_t)b * SS + start) * (HH / 4);

        // Row-parallel: wave w sums rows w, w+4, ... Lane owns float4 chunks
        // {lane, lane+64, lane+128} of the 192-float4 row.
        float4 a0 = {0.f, 0.f, 0.f, 0.f};
        float4 a1 = {0.f, 0.f, 0.f, 0.f};
        float4 a2 = {0.f, 0.f, 0.f, 0.f};
        for (int row = wid; row < len; row += 4) {
            const float4* p = base4 + (size_t)row * (HH / 4);
            const float4 u0 = p[lane];
            const float4 u1 = p[lane + 64];
            const float4 u2 = p[lane + 128];
            a0.x += u0.x; a0.y += u0.y; a0.z += u0.z; a0.w += u0.w;
            a1.x += u1.x; a1.y += u1.y; a1.z += u1.z; a1.w += u1.w;
            a2.x += u2.x; a2.y += u2.y; a2.z += u2.z; a2.w += u2.w;
        }

        __shared__ float4 partsh[4][192];   // 12 KB
        partsh[wid][lane]       = a0;
        partsh[wid][lane + 64]  = a1;
        partsh[wid][lane + 128] = a2;
        __syncthreads();

        __shared__ float redc[3][NC];
        if (tid < 192) {
            const float4 s0 = partsh[0][tid];
            const float4 s1 = partsh[1][tid];
            const float4 s2 = partsh[2][tid];
            const float4 s3 = partsh[3][tid];
            const float inv = 1.0f / (float)len;
            const float m[4] = {(s0.x + s1.x + s2.x + s3.x) * inv,
                                (s0.y + s1.y + s2.y + s3.y) * inv,
                                (s0.z + s1.z + s2.z + s3.z) * inv,
                                (s0.w + s1.w + s2.w + s3.w) * inv};

            // Contiguous W_r: thread's h-range [4*tid,4*tid+4) -> 36 floats
            // = 9 float4 loads; remap (j,q) -> (e,c) at compile time.
            const float4* wrt = (const float4*)(Wr + 36 * tid);
            float part[NC];
            #pragma unroll
            for (int c = 0; c < NC; ++c) part[c] = 0.f;
            #pragma unroll
            for (int j = 0; j < 9; ++j) {
                const float4 f = wrt[j];
                const float vv[4] = {f.x, f.y, f.z, f.w};
                #pragma unroll
                for (int q = 0; q < 4; ++q) {
                    const int flat = 4 * j + q;          // 0..35
                    part[flat % NC] += m[flat / NC] * vv[q];
                }
            }

            #pragma unroll
            for (int c = 0; c < NC; ++c)
                #pragma unroll
                for (int off = 32; off; off >>= 1)
                    part[c] += __shfl_xor(part[c], off);

            if (lane == 0) {
                #pragma unroll
                for (int c = 0; c < NC; ++c) redc[wid][c] = part[c];
            }
        }
        __syncthreads();

        if (tid == 0) {
            float l[NC];
            #pragma unroll
            for (int c = 0; c < NC; ++c)
                l[c] = redc[0][c] + redc[1][c] + redc[2][c] + br[c];
            float mx = l[0];
            #pragma unroll
            for (int c = 1; c < NC; ++c) mx = fmaxf(mx, l[c]);
            float ssum = 0.f;
            #pragma unroll
            for (int c = 0; c < NC; ++c) ssum += expf(l[c] - mx);
            const float lse = logf(ssum);
            const int   t   = rlabel[r];
            rnll[r] = -(l[t] - mx - lse);
        }
    }
}

// ---------------------------------------------------------------------------
// Final reduction (1 block, 256 threads, f64 accumulation).
// ---------------------------------------------------------------------------
__global__ __launch_bounds__(256) void fin_kernel(
    const float2* __restrict__ bdp, const float* __restrict__ rnll,
    float* __restrict__ out)
{
    const int tid  = threadIdx.x;
    const int wid  = tid >> 6;
    const int lane = tid & 63;

    double a = 0.0, c = 0.0, e = 0.0;
    for (int i = tid; i < NB_BD; i += 256) {
        const float2 p = bdp[i];
        a += (double)p.x;
        c += (double)p.y;
    }
    for (int i = tid; i < NR; i += 256) e += (double)rnll[i];

    #pragma unroll
    for (int off = 32; off; off >>= 1) {
        a += __shfl_xor(a, off);
        c += __shfl_xor(c, off);
        e += __shfl_xor(e, off);
    }

    __shared__ double sa[4], sc[4], se[4];
    if (lane == 0) { sa[wid] = a; sc[wid] = c; se[wid] = e; }
    __syncthreads();

    if (tid == 0) {
        const double A = sa[0] + sa[1] + sa[2] + sa[3];
        const double C = sc[0] + sc[1] + sc[2] + sc[3];
        const double E = se[0] + se[1] + se[2] + se[3];
        const float ent = (float)(E / (double)NR);
        const float bd  = (float)(A / (C + 1e-6));
        out[0] = 0.3f * ent + 0.7f * bd;
    }
}

extern "C" void kernel_launch(void* const* d_in, const int* in_sizes, int n_in,
                              void* d_out, int out_size, void* d_ws, size_t ws_size,
                              hipStream_t stream)
{
    const float* wr     = (const float*)d_in[0];
    const float* Ws     = (const float*)d_in[1];
    const float* bs     = (const float*)d_in[2];
    const float* Wr     = (const float*)d_in[3];
    const float* br     = (const float*)d_in[4];
    const int*   tgt    = (const int*)d_in[5];
    const int*   seg    = (const int*)d_in[6];
    const int*   rstart = (const int*)d_in[7];
    const int*   rlen   = (const int*)d_in[8];
    const int*   rbatch = (const int*)d_in[9];
    const int*   rlabel = (const int*)d_in[10];

    float2* bdp  = (float2*)d_ws;                                 // 2048 * 8 B
    float*  rnll = (float*)((char*)d_ws + NB_BD * sizeof(float2)); // 4096 * 4 B

    main_kernel<<<NBLK, 256, 0, stream>>>(wr, Ws, bs, tgt, seg,
                                          Wr, br, rstart, rlen, rbatch, rlabel,
                                          bdp, rnll);
    fin_kernel<<<1, 256, 0, stream>>>(bdp, rnll, (float*)d_out);
}